// Round 16
// baseline (203.437 us; speedup 1.0000x reference)
//
#include <hip/hip_runtime.h>
#include <hip/hip_bf16.h>
#include <hip/hip_cooperative_groups.h>
#include <string.h>

// Problem constants
#define NB    4096      // batch rows
#define IND_  512       // feature dim
#define OUTD_ 512       // output dim (GEMM M, "o")
#define XCOLS 514       // P + IND
#define ND    25        // D^P
#define KTOT  12800     // IND_*ND
#define KT2B  12928     // KTOT + 128-col bias tail (fp8 bytes per Wf8 row)

// GEMM tiling
#define BM 128
#define BN 128
#define BKB 128         // K-window per iter (fp8 bytes == elements)

// prep_w tiling (R13-proven)
#define PWI 64
#define PWO 4
#define PWC (PWO * ND)   // 100
#define PWP 104
#define OL8 72

typedef float  f32x4  __attribute__((ext_vector_type(4)));
typedef int    i32x4  __attribute__((ext_vector_type(4)));
typedef int    i32x8  __attribute__((ext_vector_type(8)));
typedef unsigned short u16x4 __attribute__((ext_vector_type(4)));
typedef unsigned int   u32x2 __attribute__((ext_vector_type(2)));

__device__ __forceinline__ unsigned short f2bf(float f) {
  unsigned int x = __float_as_uint(f);
  return (unsigned short)((x + 0x7fffu + ((x >> 16) & 1u)) >> 16);
}

__device__ __forceinline__ float bf2f(unsigned short u) {
  return __uint_as_float(((unsigned int)u) << 16);
}

__device__ __forceinline__ unsigned int pk_bf16(float a, float b) {
  return (unsigned int)f2bf(a) | ((unsigned int)f2bf(b) << 16);
}

// Software fp32 -> OCP e4m3fn, RNE, for v >= 0 (all values < 1.2).
__device__ __forceinline__ unsigned char f2fp8(float v) {
  if (v < 0.015625f) {
    return (unsigned char)__float2int_rn(v * 512.0f);
  }
  unsigned int u = __float_as_uint(v);
  u += 0x7ffffu + ((u >> 20) & 1u);
  int e = (int)(u >> 23) - 127 + 7;
  unsigned int m = (u >> 20) & 7u;
  return (unsigned char)((e << 3) | m);
}

__device__ __forceinline__ float basis_f(float t, int j) {
  switch (j) {
    case 0: return 1.0f;
    case 1: return t;
    case 2: return t * t;
    case 3: { float r = t - 0.33f; r = r > 0.0f ? r : 0.0f; return r * r; }
    default:{ float r = t - 0.66f; r = r > 0.0f ? r : 0.0f; return r * r; }
  }
}

__device__ __forceinline__ void gload_lds16(const void* g, void* l) {
  __builtin_amdgcn_global_load_lds(
      (const __attribute__((address_space(1))) void*)g,
      (__attribute__((address_space(3))) void*)l, 16, 0, 0);
}

// ---------------------------------------------------------------------------
// prep_all: ONE dispatch (R14/R15-proven, unchanged).
// ---------------------------------------------------------------------------
__global__ __launch_bounds__(256) void prep_all_kernel(
    const float* __restrict__ x, const float* __restrict__ W,
    const float* __restrict__ bias, unsigned char* __restrict__ Xf8,
    float* __restrict__ kb, unsigned char* __restrict__ kbT8,
    unsigned char* __restrict__ Wf8, float* __restrict__ out)
{
  __shared__ float tile[PWI * PWP];
  __shared__ unsigned char out8[PWC * OL8];
  const int bid = blockIdx.x;
  const int tid = threadIdx.x;

  if (bid < 1024) {
    const int b    = bid * 4 + (tid >> 6);
    const int lane = tid & 63;
    const float* xr = x + (size_t)b * XCOLS;
    const float* fp = xr + 2 + lane * 8;
    float2 a0 = *(const float2*)(fp + 0);
    float2 a1 = *(const float2*)(fp + 2);
    float2 a2 = *(const float2*)(fp + 4);
    float2 a3 = *(const float2*)(fp + 6);
    float xf[8] = {a0.x, a0.y, a1.x, a1.y, a2.x, a2.y, a3.x, a3.y};
    u32x2 pk;
    pk[0] = (unsigned int)f2fp8(xf[0]) | ((unsigned int)f2fp8(xf[1]) << 8) |
            ((unsigned int)f2fp8(xf[2]) << 16) | ((unsigned int)f2fp8(xf[3]) << 24);
    pk[1] = (unsigned int)f2fp8(xf[4]) | ((unsigned int)f2fp8(xf[5]) << 8) |
            ((unsigned int)f2fp8(xf[6]) << 16) | ((unsigned int)f2fp8(xf[7]) << 24);
    *reinterpret_cast<u32x2*>(Xf8 + (size_t)b * IND_ + lane * 8) = pk;

    float t0 = xr[0], t1 = xr[1];
    if (lane < 2) out[(size_t)b * XCOLS + lane] = (lane == 0) ? t0 : t1;
    {
      int d1 = lane / 5, d2 = lane - d1 * 5;
      float kv = basis_f(t0, d1) * basis_f(t1, d2);
      if (lane < ND) kb[(size_t)b * ND + lane] = kv;
    }
    {
      int ta = 2 * lane, tb = 2 * lane + 1;
      unsigned char ba = 0, bb = 0;
      if (ta < ND) { int d1 = ta / 5, d2 = ta - d1 * 5;
                     ba = f2fp8(basis_f(t0, d1) * basis_f(t1, d2)); }
      if (tb < ND) { int d1 = tb / 5, d2 = tb - d1 * 5;
                     bb = f2fp8(basis_f(t0, d1) * basis_f(t1, d2)); }
      *(unsigned short*)(kbT8 + (size_t)b * 128 + 2 * lane) =
          (unsigned short)ba | ((unsigned short)bb << 8);
    }
  } else if (bid < 2048) {
    const int pw = bid - 1024;
    const int i0 = (pw & 7) * PWI;
    const int o0 = (pw >> 3) * PWO;

    for (int idx = tid; idx < PWI * (PWC / 4); idx += 256) {
      int il = idx / (PWC / 4);
      int c4 = idx - il * (PWC / 4);
      float4 v = *(const float4*)(W + ((size_t)(i0 + il) * OUTD_ + o0) * ND + c4 * 4);
      *(float4*)&tile[il * PWP + c4 * 4] = v;
    }
    __syncthreads();
    if (tid < PWC) {
      #pragma unroll
      for (int j = 0; j < PWI / 8; ++j) {
        #pragma unroll
        for (int jj = 0; jj < 8; ++jj)
          out8[tid * OL8 + j * 8 + jj] = f2fp8(tile[(j * 8 + jj) * PWP + tid]);
      }
    }
    __syncthreads();
    for (int g = tid; g < PWC * (PWI / 8); g += 256) {
      int c  = g >> 3;
      int ig = g & 7;
      int d  = c % 25;
      int o_l = c / 25;
      u32x2 v = *reinterpret_cast<const u32x2*>(&out8[c * OL8 + ig * 8]);
      size_t rowb = (size_t)(o0 + o_l) * KT2B + (size_t)d * IND_ + i0;
      *reinterpret_cast<u32x2*>(Wf8 + rowb + ig * 8) = v;
    }
  } else {
    const int pt  = bid - 2048;
    const int idx = pt * 256 + tid;
    const int o = idx >> 6;
    const int p = idx & 63;
    int ta = 2 * p, tb = 2 * p + 1;
    unsigned char ba = (ta < ND) ? f2fp8(bias[o * ND + ta]) : (unsigned char)0;
    unsigned char bb = (tb < ND) ? f2fp8(bias[o * ND + tb]) : (unsigned char)0;
    *(unsigned short*)(Wf8 + (size_t)o * KT2B + KTOT + 2 * p) =
        (unsigned short)ba | ((unsigned short)bb << 8);
  }
}

// ---------------------------------------------------------------------------
// GEMM body (R15-proven, 43us) as a macro-free inline: runs the MX K-loop and
// stores bf16 partials.  Used by both the cooperative fused kernel and the
// standalone fallback.
// ---------------------------------------------------------------------------
__device__ __forceinline__ void gemm_mx_body(
    const unsigned char* __restrict__ Wf8, const unsigned char* __restrict__ Xf8,
    const float* __restrict__ kb, const unsigned char* __restrict__ kbT8,
    unsigned short* __restrict__ Pb, unsigned char* Als, unsigned char* Bls,
    int id, int tid)
{
  const int lane = tid & 63;
  const int w    = tid >> 6;
  const int l15  = lane & 15;
  const int quad = lane >> 4;

  const int xcd = id & 7;
  const int j   = id >> 3;
  const int bx  = j & 3;
  const int pg  = xcd * 16 + (j >> 2);
  const int by  = pg & 31;
  const int bz  = pg >> 5;

  const int o0 = bx * BM;
  const int b0 = by * BN;
  const int ks_begin = bz * 3200;
  const int ks_end   = (bz == 3) ? KT2B : ks_begin + 3200;

  const int o_off = (w & 1) * 64;
  const int b_off = (w >> 1) * 64;
  const int srow  = lane >> 3;
  const int scol  = ((lane & 7) ^ srow) * 16;
  const int r7    = l15 & 7;
  const int s0    = ((2 * quad) ^ r7) * 16;
  const int s1    = ((2 * quad + 1) ^ r7) * 16;

  f32x4 acc[4][4], fin[4][4];
  #pragma unroll
  for (int i = 0; i < 4; ++i)
    #pragma unroll
    for (int jj = 0; jj < 4; ++jj) { acc[i][jj] = (f32x4)0.0f; fin[i][jj] = (f32x4)0.0f; }

  float kv[4] = {1.0f, 1.0f, 1.0f, 1.0f};
  int cur_d = -1;

  for (int k0 = ks_begin; k0 < ks_end; k0 += BKB) {
    const int d = k0 >> 9;
    if (d != cur_d) {
      if (cur_d >= 0) {
        #pragma unroll
        for (int nf = 0; nf < 4; ++nf)
          #pragma unroll
          for (int mf = 0; mf < 4; ++mf)
            #pragma unroll
            for (int r = 0; r < 4; ++r) {
              fin[mf][nf][r] += kv[nf] * acc[mf][nf][r];
              acc[mf][nf][r] = 0.0f;
            }
      }
      cur_d = d;
      if (d < ND) {
        #pragma unroll
        for (int nf = 0; nf < 4; ++nf)
          kv[nf] = kb[(size_t)(b0 + b_off + nf * 16 + l15) * ND + d];
      } else {
        #pragma unroll
        for (int nf = 0; nf < 4; ++nf) kv[nf] = 1.0f;
      }
    }

    #pragma unroll
    for (int c = 0; c < 4; ++c) {
      int chunk = w * 4 + c;
      int r = chunk * 8 + srow;
      gload_lds16(Wf8 + (size_t)(o0 + r) * KT2B + k0 + scol, &Als[chunk * 1024]);
      const unsigned char* gb = (d < ND)
          ? Xf8 + (size_t)(b0 + r) * IND_ + (k0 & 511) + scol
          : kbT8 + (size_t)(b0 + r) * 128 + scol;
      gload_lds16(gb, &Bls[chunk * 1024]);
    }
    __syncthreads();

    {
      i32x8 af[4], bfr[4];
      #pragma unroll
      for (int mf = 0; mf < 4; ++mf) {
        int rb = (o_off + mf * 16 + l15) * BKB;
        i32x4 lo = *reinterpret_cast<const i32x4*>(&Als[rb + s0]);
        i32x4 hi = *reinterpret_cast<const i32x4*>(&Als[rb + s1]);
        i32x8 v;
        v[0] = lo[0]; v[1] = lo[1]; v[2] = lo[2]; v[3] = lo[3];
        v[4] = hi[0]; v[5] = hi[1]; v[6] = hi[2]; v[7] = hi[3];
        af[mf] = v;
      }
      #pragma unroll
      for (int nf = 0; nf < 4; ++nf) {
        int rb = (b_off + nf * 16 + l15) * BKB;
        i32x4 lo = *reinterpret_cast<const i32x4*>(&Bls[rb + s0]);
        i32x4 hi = *reinterpret_cast<const i32x4*>(&Bls[rb + s1]);
        i32x8 v;
        v[0] = lo[0]; v[1] = lo[1]; v[2] = lo[2]; v[3] = lo[3];
        v[4] = hi[0]; v[5] = hi[1]; v[6] = hi[2]; v[7] = hi[3];
        bfr[nf] = v;
      }
      #pragma unroll
      for (int mf = 0; mf < 4; ++mf)
        #pragma unroll
        for (int nf = 0; nf < 4; ++nf)
          acc[mf][nf] = __builtin_amdgcn_mfma_scale_f32_16x16x128_f8f6f4(
              af[mf], bfr[nf], acc[mf][nf],
              0, 0, 0, 0x7f7f7f7f, 0, 0x7f7f7f7f);
    }
    __syncthreads();
  }

  #pragma unroll
  for (int nf = 0; nf < 4; ++nf)
    #pragma unroll
    for (int mf = 0; mf < 4; ++mf)
      #pragma unroll
      for (int r = 0; r < 4; ++r)
        fin[mf][nf][r] += kv[nf] * acc[mf][nf][r];

  unsigned short* Pz = Pb + (size_t)bz * NB * OUTD_;
  #pragma unroll
  for (int mf = 0; mf < 4; ++mf)
    #pragma unroll
    for (int nf = 0; nf < 4; ++nf) {
      int bg = b0 + b_off + nf * 16 + l15;
      int og = o0 + o_off + mf * 16 + quad * 4;
      u32x2 pk;
      pk[0] = pk_bf16(fin[mf][nf][0], fin[mf][nf][1]);
      pk[1] = pk_bf16(fin[mf][nf][2], fin[mf][nf][3]);
      *reinterpret_cast<u32x2*>(&Pz[(size_t)bg * OUTD_ + og]) = pk;
    }
}

__device__ __forceinline__ void epilogue_chunk(
    const unsigned short* __restrict__ Pb, float* __restrict__ out,
    int idx)   // output element index, multiple of 4
{
  const int b = idx >> 9;
  const int o = idx & 511;
  const size_t ps = (size_t)NB * OUTD_;
  float s[4] = {0.0f, 0.0f, 0.0f, 0.0f};
  #pragma unroll
  for (int z = 0; z < 4; ++z) {
    u16x4 v = *reinterpret_cast<const u16x4*>(&Pb[z * ps + idx]);
    #pragma unroll
    for (int e = 0; e < 4; ++e) s[e] += bf2f(v[e]);
  }
  float* op = out + (size_t)b * XCOLS + 2 + o;
  float2 lo, hi;
  lo.x = s[0] > 0.0f ? s[0] : 0.0f;
  lo.y = s[1] > 0.0f ? s[1] : 0.0f;
  hi.x = s[2] > 0.0f ? s[2] : 0.0f;
  hi.y = s[3] > 0.0f ? s[3] : 0.0f;
  *(float2*)op = lo;
  *(float2*)(op + 2) = hi;
}

// ---------------------------------------------------------------------------
// Cooperative fused kernel: gemm -> ONE coordinated grid.sync -> epilogue.
// Saves one dispatch boundary + the epilogue launch (~86us aux, ~20us real
// work -> boundaries dominate).  Unlike R9 (staggered per-block fences under
// live MFMA = L2-flush storm) this is a single quiesced sync; unlike R12 the
// LDS is the exact R15 arrays (NO union — R12's 4e7-conflict suspect).
// ---------------------------------------------------------------------------
__global__ __launch_bounds__(256, 2) void gemm_epi_coop_kernel(
    const unsigned char* __restrict__ Wf8, const unsigned char* __restrict__ Xf8,
    const float* __restrict__ kb, const unsigned char* __restrict__ kbT8,
    unsigned short* __restrict__ Pb, float* __restrict__ out)
{
  __shared__ unsigned char Als[BM * BKB];   // 16 KB
  __shared__ unsigned char Bls[BN * BKB];   // 16 KB
  const int id  = blockIdx.x;
  const int tid = threadIdx.x;

  gemm_mx_body(Wf8, Xf8, kb, kbT8, Pb, Als, Bls, id, tid);

  cooperative_groups::this_grid().sync();

  // epilogue: block id handles outputs [id*4096, id*4096+4096)
  for (int t = tid; t < 1024; t += 256)
    epilogue_chunk(Pb, out, id * 4096 + t * 4);
}

// ---------------------------------------------------------------------------
// Fallback standalone kernels (R15 path, 128.8us) if coop launch is rejected.
// ---------------------------------------------------------------------------
__global__ __launch_bounds__(256, 2) void gemm_mx_kernel(
    const unsigned char* __restrict__ Wf8, const unsigned char* __restrict__ Xf8,
    const float* __restrict__ kb, const unsigned char* __restrict__ kbT8,
    unsigned short* __restrict__ Pb)
{
  __shared__ unsigned char Als[BM * BKB];
  __shared__ unsigned char Bls[BN * BKB];
  gemm_mx_body(Wf8, Xf8, kb, kbT8, Pb, Als, Bls, blockIdx.x, threadIdx.x);
}

__global__ __launch_bounds__(256) void epilogue_kernel(
    const unsigned short* __restrict__ Pb, float* __restrict__ out)
{
  epilogue_chunk(Pb, out, (blockIdx.x * 256 + threadIdx.x) * 4);
}

// ---------------------------------------------------------------------------
extern "C" void kernel_launch(void* const* d_in, const int* in_sizes, int n_in,
                              void* d_out, int out_size, void* d_ws, size_t ws_size,
                              hipStream_t stream) {
  const float* x    = (const float*)d_in[0];   // 4096 x 514
  const float* W    = (const float*)d_in[1];   // 512 x 512 x 25
  const float* bias = (const float*)d_in[2];   // 512 x 25
  float* out = (float*)d_out;
  char* ws = (char*)d_ws;

  // ws layout (bytes):
  //   Xf8 2,097,152 | Wf8 512*12928 = 6,619,136 | kb 409,600
  //   kbT8 524,288 | Pb 16,777,216   (total ~26.4 MB)
  const size_t xf_off  = 0;
  const size_t wf_off  = 2097152;
  const size_t kb_off  = wf_off + (size_t)OUTD_ * KT2B;
  const size_t kbt_off = kb_off + 409600;
  const size_t p_off   = kbt_off + (size_t)NB * 128;
  unsigned char* Xf8  = (unsigned char*)(ws + xf_off);
  unsigned char* Wf8  = (unsigned char*)(ws + wf_off);
  float* kb           = (float*)(ws + kb_off);
  unsigned char* kbT8 = (unsigned char*)(ws + kbt_off);
  unsigned short* Pb  = (unsigned short*)(ws + p_off);

  prep_all_kernel<<<2176, 256, 0, stream>>>(x, W, bias, Xf8, kb, kbT8, Wf8, out);

  void* args[] = {(void*)&Wf8, (void*)&Xf8, (void*)&kb, (void*)&kbT8,
                  (void*)&Pb, (void*)&out};
  hipError_t e = hipLaunchCooperativeKernel((void*)gemm_epi_coop_kernel,
                                            dim3(512), dim3(256), args, 0, stream);
  if (e != hipSuccess) {
    gemm_mx_kernel<<<512, 256, 0, stream>>>(Wf8, Xf8, kb, kbT8, Pb);
    epilogue_kernel<<<(NB * OUTD_) / 1024, 256, 0, stream>>>(Pb, out);
  }
}

// Round 17
// 139.210 us; speedup vs baseline: 1.4614x; 1.4614x over previous
//
#include <hip/hip_runtime.h>
#include <hip/hip_bf16.h>
#include <string.h>

// Problem constants
#define NB    4096      // batch rows
#define IND_  512       // feature dim
#define OUTD_ 512       // output dim (GEMM M, "o")
#define XCOLS 514       // P + IND
#define ND    25        // D^P
#define KTOT  12800     // IND_*ND
#define KT2B  12928     // KTOT + 128-col bias tail (fp8 bytes per Wf8 row)
#define NSPL  8         // split-K count (R17: 1024 blocks = 4/CU resident)
#define NITER 101       // KT2B / 128

// GEMM tiling
#define BM 128
#define BN 128
#define BKB 128         // K-window per iter (fp8 bytes == elements)

// prep_w tiling (R13-proven)
#define PWI 64
#define PWO 4
#define PWC (PWO * ND)   // 100
#define PWP 104
#define OL8 72

typedef float  f32x4  __attribute__((ext_vector_type(4)));
typedef int    i32x4  __attribute__((ext_vector_type(4)));
typedef int    i32x8  __attribute__((ext_vector_type(8)));
typedef unsigned short u16x4 __attribute__((ext_vector_type(4)));
typedef unsigned int   u32x2 __attribute__((ext_vector_type(2)));

__device__ __forceinline__ unsigned short f2bf(float f) {
  unsigned int x = __float_as_uint(f);
  return (unsigned short)((x + 0x7fffu + ((x >> 16) & 1u)) >> 16);
}

__device__ __forceinline__ float bf2f(unsigned short u) {
  return __uint_as_float(((unsigned int)u) << 16);
}

__device__ __forceinline__ unsigned int pk_bf16(float a, float b) {
  return (unsigned int)f2bf(a) | ((unsigned int)f2bf(b) << 16);
}

// Software fp32 -> OCP e4m3fn, RNE, for v >= 0 (all values < 1.2).
__device__ __forceinline__ unsigned char f2fp8(float v) {
  if (v < 0.015625f) {
    return (unsigned char)__float2int_rn(v * 512.0f);
  }
  unsigned int u = __float_as_uint(v);
  u += 0x7ffffu + ((u >> 20) & 1u);
  int e = (int)(u >> 23) - 127 + 7;
  unsigned int m = (u >> 20) & 7u;
  return (unsigned char)((e << 3) | m);
}

__device__ __forceinline__ float basis_f(float t, int j) {
  switch (j) {
    case 0: return 1.0f;
    case 1: return t;
    case 2: return t * t;
    case 3: { float r = t - 0.33f; r = r > 0.0f ? r : 0.0f; return r * r; }
    default:{ float r = t - 0.66f; r = r > 0.0f ? r : 0.0f; return r * r; }
  }
}

__device__ __forceinline__ void gload_lds16(const void* g, void* l) {
  __builtin_amdgcn_global_load_lds(
      (const __attribute__((address_space(1))) void*)g,
      (__attribute__((address_space(3))) void*)l, 16, 0, 0);
}

// ---------------------------------------------------------------------------
// prep_all: ONE dispatch (R14/R15-proven, unchanged).
// Lessons: R9 — cross-block handoff = kernel boundary only; R12/R16 —
// grid.sync costs ~50us at 512 blocks, never fuse via cooperative launch.
// ---------------------------------------------------------------------------
__global__ __launch_bounds__(256) void prep_all_kernel(
    const float* __restrict__ x, const float* __restrict__ W,
    const float* __restrict__ bias, unsigned char* __restrict__ Xf8,
    float* __restrict__ kb, unsigned char* __restrict__ kbT8,
    unsigned char* __restrict__ Wf8, float* __restrict__ out)
{
  __shared__ float tile[PWI * PWP];
  __shared__ unsigned char out8[PWC * OL8];
  const int bid = blockIdx.x;
  const int tid = threadIdx.x;

  if (bid < 1024) {
    const int b    = bid * 4 + (tid >> 6);
    const int lane = tid & 63;
    const float* xr = x + (size_t)b * XCOLS;
    const float* fp = xr + 2 + lane * 8;
    float2 a0 = *(const float2*)(fp + 0);
    float2 a1 = *(const float2*)(fp + 2);
    float2 a2 = *(const float2*)(fp + 4);
    float2 a3 = *(const float2*)(fp + 6);
    float xf[8] = {a0.x, a0.y, a1.x, a1.y, a2.x, a2.y, a3.x, a3.y};
    u32x2 pk;
    pk[0] = (unsigned int)f2fp8(xf[0]) | ((unsigned int)f2fp8(xf[1]) << 8) |
            ((unsigned int)f2fp8(xf[2]) << 16) | ((unsigned int)f2fp8(xf[3]) << 24);
    pk[1] = (unsigned int)f2fp8(xf[4]) | ((unsigned int)f2fp8(xf[5]) << 8) |
            ((unsigned int)f2fp8(xf[6]) << 16) | ((unsigned int)f2fp8(xf[7]) << 24);
    *reinterpret_cast<u32x2*>(Xf8 + (size_t)b * IND_ + lane * 8) = pk;

    float t0 = xr[0], t1 = xr[1];
    if (lane < 2) out[(size_t)b * XCOLS + lane] = (lane == 0) ? t0 : t1;
    {
      int d1 = lane / 5, d2 = lane - d1 * 5;
      float kv = basis_f(t0, d1) * basis_f(t1, d2);
      if (lane < ND) kb[(size_t)b * ND + lane] = kv;
    }
    {
      int ta = 2 * lane, tb = 2 * lane + 1;
      unsigned char ba = 0, bb = 0;
      if (ta < ND) { int d1 = ta / 5, d2 = ta - d1 * 5;
                     ba = f2fp8(basis_f(t0, d1) * basis_f(t1, d2)); }
      if (tb < ND) { int d1 = tb / 5, d2 = tb - d1 * 5;
                     bb = f2fp8(basis_f(t0, d1) * basis_f(t1, d2)); }
      *(unsigned short*)(kbT8 + (size_t)b * 128 + 2 * lane) =
          (unsigned short)ba | ((unsigned short)bb << 8);
    }
  } else if (bid < 2048) {
    const int pw = bid - 1024;
    const int i0 = (pw & 7) * PWI;
    const int o0 = (pw >> 3) * PWO;

    for (int idx = tid; idx < PWI * (PWC / 4); idx += 256) {
      int il = idx / (PWC / 4);
      int c4 = idx - il * (PWC / 4);
      float4 v = *(const float4*)(W + ((size_t)(i0 + il) * OUTD_ + o0) * ND + c4 * 4);
      *(float4*)&tile[il * PWP + c4 * 4] = v;
    }
    __syncthreads();
    if (tid < PWC) {
      #pragma unroll
      for (int j = 0; j < PWI / 8; ++j) {
        #pragma unroll
        for (int jj = 0; jj < 8; ++jj)
          out8[tid * OL8 + j * 8 + jj] = f2fp8(tile[(j * 8 + jj) * PWP + tid]);
      }
    }
    __syncthreads();
    for (int g = tid; g < PWC * (PWI / 8); g += 256) {
      int c  = g >> 3;
      int ig = g & 7;
      int d  = c % 25;
      int o_l = c / 25;
      u32x2 v = *reinterpret_cast<const u32x2*>(&out8[c * OL8 + ig * 8]);
      size_t rowb = (size_t)(o0 + o_l) * KT2B + (size_t)d * IND_ + i0;
      *reinterpret_cast<u32x2*>(Wf8 + rowb + ig * 8) = v;
    }
  } else {
    const int pt  = bid - 2048;
    const int idx = pt * 256 + tid;
    const int o = idx >> 6;
    const int p = idx & 63;
    int ta = 2 * p, tb = 2 * p + 1;
    unsigned char ba = (ta < ND) ? f2fp8(bias[o * ND + ta]) : (unsigned char)0;
    unsigned char bb = (tb < ND) ? f2fp8(bias[o * ND + tb]) : (unsigned char)0;
    *(unsigned short*)(Wf8 + (size_t)o * KT2B + KTOT + 2 * p) =
        (unsigned short)ba | ((unsigned short)bb << 8);
  }
}

// ---------------------------------------------------------------------------
// gemm_mx: R15-proven MX K-loop (43us @ S=4), now split-K NSPL=8 -> 1024
// blocks = 4 resident blocks/CU (VGPR 112 <= 128, LDS 32KB: HW fits 4; R2/R6
// lesson: raise occupancy via GRID, never via __launch_bounds__(256,4)).
// XCD map: id%8 = XCD; each XCD owns split bz==xcd (Wf8 slice ~0.85MB +
// Xf8 2MB fit its 4MB L2) x 4 o-tiles x 32 b-tiles.
// Splits may start/end mid-phase (R11 linearity).
// ---------------------------------------------------------------------------
__global__ __launch_bounds__(256, 2) void gemm_mx_kernel(
    const unsigned char* __restrict__ Wf8, const unsigned char* __restrict__ Xf8,
    const float* __restrict__ kb, const unsigned char* __restrict__ kbT8,
    unsigned short* __restrict__ Pb)
{
  __shared__ unsigned char Als[BM * BKB];   // 16 KB
  __shared__ unsigned char Bls[BN * BKB];   // 16 KB

  const int tid  = threadIdx.x;
  const int lane = tid & 63;
  const int w    = tid >> 6;
  const int l15  = lane & 15;
  const int quad = lane >> 4;

  const int id  = blockIdx.x;           // [0,1024)
  const int xcd = id & 7;
  const int j   = id >> 3;              // [0,128)
  const int bx  = j & 3;                // o-tile
  const int pg  = xcd * 32 + (j >> 2);  // [0,256): (b-tile, split)
  const int by  = pg & 31;
  const int bz  = pg >> 5;              // split [0,8) == xcd

  const int o0 = bx * BM;
  const int b0 = by * BN;
  const int ks_begin = ((bz * NITER) >> 3) * BKB;
  const int ks_end   = (((bz + 1) * NITER) >> 3) * BKB;

  const int o_off = (w & 1) * 64;
  const int b_off = (w >> 1) * 64;
  const int srow  = lane >> 3;
  const int scol  = ((lane & 7) ^ srow) * 16;
  const int r7    = l15 & 7;
  const int s0    = ((2 * quad) ^ r7) * 16;
  const int s1    = ((2 * quad + 1) ^ r7) * 16;

  f32x4 acc[4][4], fin[4][4];
  #pragma unroll
  for (int i = 0; i < 4; ++i)
    #pragma unroll
    for (int jj = 0; jj < 4; ++jj) { acc[i][jj] = (f32x4)0.0f; fin[i][jj] = (f32x4)0.0f; }

  float kv[4] = {1.0f, 1.0f, 1.0f, 1.0f};
  int cur_d = -1;

  for (int k0 = ks_begin; k0 < ks_end; k0 += BKB) {
    const int d = k0 >> 9;            // 25 => bias tail
    if (d != cur_d) {
      if (cur_d >= 0) {
        #pragma unroll
        for (int nf = 0; nf < 4; ++nf)
          #pragma unroll
          for (int mf = 0; mf < 4; ++mf)
            #pragma unroll
            for (int r = 0; r < 4; ++r) {
              fin[mf][nf][r] += kv[nf] * acc[mf][nf][r];
              acc[mf][nf][r] = 0.0f;
            }
      }
      cur_d = d;
      if (d < ND) {
        #pragma unroll
        for (int nf = 0; nf < 4; ++nf)
          kv[nf] = kb[(size_t)(b0 + b_off + nf * 16 + l15) * ND + d];
      } else {
        #pragma unroll
        for (int nf = 0; nf < 4; ++nf) kv[nf] = 1.0f;
      }
    }

    // stage A + B: 16 chunks each of 1KB (8 rows x 128B); wave w: 4 + 4
    #pragma unroll
    for (int c = 0; c < 4; ++c) {
      int chunk = w * 4 + c;
      int r = chunk * 8 + srow;
      gload_lds16(Wf8 + (size_t)(o0 + r) * KT2B + k0 + scol, &Als[chunk * 1024]);
      const unsigned char* gb = (d < ND)
          ? Xf8 + (size_t)(b0 + r) * IND_ + (k0 & 511) + scol
          : kbT8 + (size_t)(b0 + r) * 128 + scol;
      gload_lds16(gb, &Bls[chunk * 1024]);
    }
    __syncthreads();

    // one K=128 scaled MFMA per frag pair (unit scales = exact fp8)
    {
      i32x8 af[4], bfr[4];
      #pragma unroll
      for (int mf = 0; mf < 4; ++mf) {
        int rb = (o_off + mf * 16 + l15) * BKB;
        i32x4 lo = *reinterpret_cast<const i32x4*>(&Als[rb + s0]);
        i32x4 hi = *reinterpret_cast<const i32x4*>(&Als[rb + s1]);
        i32x8 v;
        v[0] = lo[0]; v[1] = lo[1]; v[2] = lo[2]; v[3] = lo[3];
        v[4] = hi[0]; v[5] = hi[1]; v[6] = hi[2]; v[7] = hi[3];
        af[mf] = v;
      }
      #pragma unroll
      for (int nf = 0; nf < 4; ++nf) {
        int rb = (b_off + nf * 16 + l15) * BKB;
        i32x4 lo = *reinterpret_cast<const i32x4*>(&Bls[rb + s0]);
        i32x4 hi = *reinterpret_cast<const i32x4*>(&Bls[rb + s1]);
        i32x8 v;
        v[0] = lo[0]; v[1] = lo[1]; v[2] = lo[2]; v[3] = lo[3];
        v[4] = hi[0]; v[5] = hi[1]; v[6] = hi[2]; v[7] = hi[3];
        bfr[nf] = v;
      }
      #pragma unroll
      for (int mf = 0; mf < 4; ++mf)
        #pragma unroll
        for (int nf = 0; nf < 4; ++nf)
          acc[mf][nf] = __builtin_amdgcn_mfma_scale_f32_16x16x128_f8f6f4(
              af[mf], bfr[nf], acc[mf][nf],
              0, 0, 0, 0x7f7f7f7f, 0, 0x7f7f7f7f);
    }
    __syncthreads();
  }

  // final flush
  #pragma unroll
  for (int nf = 0; nf < 4; ++nf)
    #pragma unroll
    for (int mf = 0; mf < 4; ++mf)
      #pragma unroll
      for (int r = 0; r < 4; ++r)
        fin[mf][nf][r] += kv[nf] * acc[mf][nf][r];

  // store partial as bf16
  unsigned short* Pz = Pb + (size_t)bz * NB * OUTD_;
  #pragma unroll
  for (int mf = 0; mf < 4; ++mf)
    #pragma unroll
    for (int nf = 0; nf < 4; ++nf) {
      int bg = b0 + b_off + nf * 16 + l15;
      int og = o0 + o_off + mf * 16 + quad * 4;
      u32x2 pk;
      pk[0] = pk_bf16(fin[mf][nf][0], fin[mf][nf][1]);
      pk[1] = pk_bf16(fin[mf][nf][2], fin[mf][nf][3]);
      *reinterpret_cast<u32x2*>(&Pz[(size_t)bg * OUTD_ + og]) = pk;
    }
}

// ---------------------------------------------------------------------------
// epilogue: out[b][2+o..2+o+3] = relu(sum of 8 partials)  (bias in K-tail)
// ---------------------------------------------------------------------------
__global__ __launch_bounds__(256) void epilogue_kernel(
    const unsigned short* __restrict__ Pb, float* __restrict__ out)
{
  const int idx = (blockIdx.x * 256 + threadIdx.x) * 4;   // < 4096*512
  const int b = idx >> 9;
  const int o = idx & 511;
  const size_t ps = (size_t)NB * OUTD_;
  float s[4] = {0.0f, 0.0f, 0.0f, 0.0f};
  #pragma unroll
  for (int z = 0; z < NSPL; ++z) {
    u16x4 v = *reinterpret_cast<const u16x4*>(&Pb[z * ps + idx]);
    #pragma unroll
    for (int e = 0; e < 4; ++e) s[e] += bf2f(v[e]);
  }
  float* op = out + (size_t)b * XCOLS + 2 + o;   // 8B-aligned
  float2 lo, hi;
  lo.x = s[0] > 0.0f ? s[0] : 0.0f;
  lo.y = s[1] > 0.0f ? s[1] : 0.0f;
  hi.x = s[2] > 0.0f ? s[2] : 0.0f;
  hi.y = s[3] > 0.0f ? s[3] : 0.0f;
  *(float2*)op = lo;
  *(float2*)(op + 2) = hi;
}

// ---------------------------------------------------------------------------
extern "C" void kernel_launch(void* const* d_in, const int* in_sizes, int n_in,
                              void* d_out, int out_size, void* d_ws, size_t ws_size,
                              hipStream_t stream) {
  const float* x    = (const float*)d_in[0];   // 4096 x 514
  const float* W    = (const float*)d_in[1];   // 512 x 512 x 25
  const float* bias = (const float*)d_in[2];   // 512 x 25
  float* out = (float*)d_out;
  char* ws = (char*)d_ws;

  // ws layout (bytes):
  //   Xf8 2,097,152 | Wf8 512*12928 = 6,619,136 | kb 409,600
  //   kbT8 524,288 | Pb 8*4096*512*2 = 33,554,432   (total ~43.2 MB)
  const size_t xf_off  = 0;
  const size_t wf_off  = 2097152;
  const size_t kb_off  = wf_off + (size_t)OUTD_ * KT2B;
  const size_t kbt_off = kb_off + 409600;
  const size_t p_off   = kbt_off + (size_t)NB * 128;
  unsigned char* Xf8  = (unsigned char*)(ws + xf_off);
  unsigned char* Wf8  = (unsigned char*)(ws + wf_off);
  float* kb           = (float*)(ws + kb_off);
  unsigned char* kbT8 = (unsigned char*)(ws + kbt_off);
  unsigned short* Pb  = (unsigned short*)(ws + p_off);

  prep_all_kernel<<<2176, 256, 0, stream>>>(x, W, bias, Xf8, kb, kbT8, Wf8, out);
  gemm_mx_kernel<<<1024, 256, 0, stream>>>(Wf8, Xf8, kb, kbT8, Pb);
  epilogue_kernel<<<(NB * OUTD_) / 1024, 256, 0, stream>>>(Pb, out);
}

// Round 18
// 127.251 us; speedup vs baseline: 1.5987x; 1.0940x over previous
//
#include <hip/hip_runtime.h>
#include <hip/hip_bf16.h>
#include <string.h>

// Problem constants
#define NB    4096      // batch rows
#define IND_  512       // feature dim
#define OUTD_ 512       // output dim (GEMM M, "o")
#define XCOLS 514       // P + IND
#define ND    25        // D^P
#define KTOT  12800     // IND_*ND
#define KT2B  12928     // KTOT + 128-col bias tail (fp8 bytes per Wf8 row)
#define NSPL  4         // split-K (R15-proven; R17's S=8 regressed)

// GEMM tiling
#define BM 128
#define BN 128
#define BKB 128         // K-window per iter (fp8 bytes == elements)

// prep_w tiling (v2: balanced f2fp8 in load stage, byte LDS tile)
#define PWI 64
#define PWO 4
#define PWC (PWO * ND)   // 100 columns (o_l*25 + d)
#define T8P 112          // tile8 padded byte stride (rows x 112B; bank-clean)

typedef float  f32x4  __attribute__((ext_vector_type(4)));
typedef int    i32x4  __attribute__((ext_vector_type(4)));
typedef int    i32x8  __attribute__((ext_vector_type(8)));
typedef unsigned short u16x4 __attribute__((ext_vector_type(4)));
typedef unsigned int   u32x2 __attribute__((ext_vector_type(2)));

__device__ __forceinline__ unsigned short f2bf(float f) {
  unsigned int x = __float_as_uint(f);
  return (unsigned short)((x + 0x7fffu + ((x >> 16) & 1u)) >> 16);
}

__device__ __forceinline__ float bf2f(unsigned short u) {
  return __uint_as_float(((unsigned int)u) << 16);
}

__device__ __forceinline__ unsigned int pk_bf16(float a, float b) {
  return (unsigned int)f2bf(a) | ((unsigned int)f2bf(b) << 16);
}

// Software fp32 -> OCP e4m3fn, RNE, for v >= 0 (all values < 1.2).
__device__ __forceinline__ unsigned char f2fp8(float v) {
  if (v < 0.015625f) {
    return (unsigned char)__float2int_rn(v * 512.0f);
  }
  unsigned int u = __float_as_uint(v);
  u += 0x7ffffu + ((u >> 20) & 1u);
  int e = (int)(u >> 23) - 127 + 7;
  unsigned int m = (u >> 20) & 7u;
  return (unsigned char)((e << 3) | m);
}

__device__ __forceinline__ float basis_f(float t, int j) {
  switch (j) {
    case 0: return 1.0f;
    case 1: return t;
    case 2: return t * t;
    case 3: { float r = t - 0.33f; r = r > 0.0f ? r : 0.0f; return r * r; }
    default:{ float r = t - 0.66f; r = r > 0.0f ? r : 0.0f; return r * r; }
  }
}

__device__ __forceinline__ void gload_lds16(const void* g, void* l) {
  __builtin_amdgcn_global_load_lds(
      (const __attribute__((address_space(1))) void*)g,
      (__attribute__((address_space(3))) void*)l, 16, 0, 0);
}

// ---------------------------------------------------------------------------
// prep_all v2: ONE dispatch, 1536 blocks.
//   [0,512):    prep_x — 8 rows/block (2 per wave): Xf8, kb fp32, kbT8, out[0:2]
//   [512,1536): prep_w — W[i,o,d] fp32 -> Wf8[o][d*512+i] fp8 (stride KT2B).
//               v2: f2fp8 in the LOAD stage (all 256 threads, ~25 conv each —
//               v1 packed on 100 threads x 64 conv = 3x imbalance); LDS holds
//               bytes; store stage = conflict-free byte gather (stride 112B ->
//               banks {0,28,24,20,16,12,8,4}) + coalesced 8B writes.
//               i0==0 blocks also write their 4 o's bias K-tail.
// Lessons: R9/R16 — cross-block handoff must be a kernel boundary (grid.sync
// = ~55us, fence storm = 3ms); R12 — no LDS unions.
// ---------------------------------------------------------------------------
__global__ __launch_bounds__(256) void prep_all_kernel(
    const float* __restrict__ x, const float* __restrict__ W,
    const float* __restrict__ bias, unsigned char* __restrict__ Xf8,
    float* __restrict__ kb, unsigned char* __restrict__ kbT8,
    unsigned char* __restrict__ Wf8, float* __restrict__ out)
{
  __shared__ unsigned char tile8[PWI * T8P];   // 7 KB
  const int bid = blockIdx.x;
  const int tid = threadIdx.x;

  if (bid < 512) {
    // ---- prep_x: 8 rows per block ----
    const int lane = tid & 63;
    #pragma unroll
    for (int rr = 0; rr < 2; ++rr) {
      const int b = bid * 8 + (tid >> 6) * 2 + rr;
      const float* xr = x + (size_t)b * XCOLS;
      const float* fp = xr + 2 + lane * 8;
      float2 a0 = *(const float2*)(fp + 0);
      float2 a1 = *(const float2*)(fp + 2);
      float2 a2 = *(const float2*)(fp + 4);
      float2 a3 = *(const float2*)(fp + 6);
      float xf[8] = {a0.x, a0.y, a1.x, a1.y, a2.x, a2.y, a3.x, a3.y};
      u32x2 pk;
      pk[0] = (unsigned int)f2fp8(xf[0]) | ((unsigned int)f2fp8(xf[1]) << 8) |
              ((unsigned int)f2fp8(xf[2]) << 16) | ((unsigned int)f2fp8(xf[3]) << 24);
      pk[1] = (unsigned int)f2fp8(xf[4]) | ((unsigned int)f2fp8(xf[5]) << 8) |
              ((unsigned int)f2fp8(xf[6]) << 16) | ((unsigned int)f2fp8(xf[7]) << 24);
      *reinterpret_cast<u32x2*>(Xf8 + (size_t)b * IND_ + lane * 8) = pk;

      float t0 = xr[0], t1 = xr[1];
      if (lane < 2) out[(size_t)b * XCOLS + lane] = (lane == 0) ? t0 : t1;
      {
        int d1 = lane / 5, d2 = lane - d1 * 5;
        float kv = basis_f(t0, d1) * basis_f(t1, d2);
        if (lane < ND) kb[(size_t)b * ND + lane] = kv;
      }
      {
        int ta = 2 * lane, tb = 2 * lane + 1;
        unsigned char ba = 0, bb = 0;
        if (ta < ND) { int d1 = ta / 5, d2 = ta - d1 * 5;
                       ba = f2fp8(basis_f(t0, d1) * basis_f(t1, d2)); }
        if (tb < ND) { int d1 = tb / 5, d2 = tb - d1 * 5;
                       bb = f2fp8(basis_f(t0, d1) * basis_f(t1, d2)); }
        *(unsigned short*)(kbT8 + (size_t)b * 128 + 2 * lane) =
            (unsigned short)ba | ((unsigned short)bb << 8);
      }
    }
  } else {
    // ---- prep_w v2: unit = (i-tile of 64, o-tile of 4) ----
    const int pw = bid - 512;
    const int i0 = (pw & 7) * PWI;     // 8 i-tiles
    const int o0 = (pw >> 3) * PWO;    // 128 o-tiles

    // load+convert: 1600 float4 over 256 threads (25 f2fp8 each, balanced)
    for (int t = tid; t < PWI * (PWC / 4); t += 256) {
      int il = t / (PWC / 4);
      int c4 = t - il * (PWC / 4);
      float4 v = *(const float4*)(W + ((size_t)(i0 + il) * OUTD_ + o0) * ND + c4 * 4);
      unsigned int pk = (unsigned int)f2fp8(v.x) | ((unsigned int)f2fp8(v.y) << 8) |
                        ((unsigned int)f2fp8(v.z) << 16) | ((unsigned int)f2fp8(v.w) << 24);
      *(unsigned int*)&tile8[il * T8P + c4 * 4] = pk;
    }
    __syncthreads();

    // store: 800 (col, i-granule) tasks; byte-gather (conflict-free) + 8B write
    for (int g = tid; g < PWC * (PWI / 8); g += 256) {
      int c  = g >> 3;          // column = o_l*25 + d
      int ig = g & 7;           // i-granule
      int d  = c % 25;
      int o_l = c / 25;
      unsigned long long v = 0;
      #pragma unroll
      for (int jj = 0; jj < 8; ++jj)
        v |= (unsigned long long)tile8[(ig * 8 + jj) * T8P + c] << (8 * jj);
      size_t rowb = (size_t)(o0 + o_l) * KT2B + (size_t)d * IND_ + i0;
      *reinterpret_cast<unsigned long long*>(Wf8 + rowb + ig * 8) = v;
    }

    // bias K-tail: i0==0 blocks cover their 4 o's (256 u16-pair tasks)
    if ((pw & 7) == 0) {
      int o = o0 + (tid >> 6);
      int p = tid & 63;
      int ta = 2 * p, tb = 2 * p + 1;
      unsigned char ba = (ta < ND) ? f2fp8(bias[o * ND + ta]) : (unsigned char)0;
      unsigned char bb = (tb < ND) ? f2fp8(bias[o * ND + tb]) : (unsigned char)0;
      *(unsigned short*)(Wf8 + (size_t)o * KT2B + KTOT + 2 * p) =
          (unsigned short)ba | ((unsigned short)bb << 8);
    }
  }
}

// ---------------------------------------------------------------------------
// gemm_mx: EXACT R15 structure (43.1us measured): split-K 4, 512 blocks,
// 2-barrier K-loop, global_load_lds x16 both operands, 16B-segment XOR
// swizzle, XCD map, (256,2), mfma_scale_f32_16x16x128_f8f6f4 w/ unit scales,
// phase-boundary fp32 kb scale, bf16 partials.
// R17 lesson: S=8/1024 blocks did NOT raise occupancy and regressed 12%.
// ---------------------------------------------------------------------------
__global__ __launch_bounds__(256, 2) void gemm_mx_kernel(
    const unsigned char* __restrict__ Wf8, const unsigned char* __restrict__ Xf8,
    const float* __restrict__ kb, const unsigned char* __restrict__ kbT8,
    unsigned short* __restrict__ Pb)
{
  __shared__ unsigned char Als[BM * BKB];   // 16 KB
  __shared__ unsigned char Bls[BN * BKB];   // 16 KB

  const int tid  = threadIdx.x;
  const int lane = tid & 63;
  const int w    = tid >> 6;
  const int l15  = lane & 15;
  const int quad = lane >> 4;

  const int id  = blockIdx.x;           // [0,512)
  const int xcd = id & 7;
  const int j   = id >> 3;              // [0,64)
  const int bx  = j & 3;                // o-tile
  const int pg  = xcd * 16 + (j >> 2);  // [0,128): (b-tile, split)
  const int by  = pg & 31;
  const int bz  = pg >> 5;              // split [0,4)

  const int o0 = bx * BM;
  const int b0 = by * BN;
  const int ks_begin = bz * 3200;                   // 25 iters x 128
  const int ks_end   = (bz == 3) ? KT2B : ks_begin + 3200;

  const int o_off = (w & 1) * 64;
  const int b_off = (w >> 1) * 64;
  const int srow  = lane >> 3;
  const int scol  = ((lane & 7) ^ srow) * 16;
  const int r7    = l15 & 7;
  const int s0    = ((2 * quad) ^ r7) * 16;
  const int s1    = ((2 * quad + 1) ^ r7) * 16;

  f32x4 acc[4][4], fin[4][4];
  #pragma unroll
  for (int i = 0; i < 4; ++i)
    #pragma unroll
    for (int jj = 0; jj < 4; ++jj) { acc[i][jj] = (f32x4)0.0f; fin[i][jj] = (f32x4)0.0f; }

  float kv[4] = {1.0f, 1.0f, 1.0f, 1.0f};
  int cur_d = -1;

  for (int k0 = ks_begin; k0 < ks_end; k0 += BKB) {
    const int d = k0 >> 9;            // 25 => bias tail
    if (d != cur_d) {
      if (cur_d >= 0) {
        #pragma unroll
        for (int nf = 0; nf < 4; ++nf)
          #pragma unroll
          for (int mf = 0; mf < 4; ++mf)
            #pragma unroll
            for (int r = 0; r < 4; ++r) {
              fin[mf][nf][r] += kv[nf] * acc[mf][nf][r];
              acc[mf][nf][r] = 0.0f;
            }
      }
      cur_d = d;
      if (d < ND) {
        #pragma unroll
        for (int nf = 0; nf < 4; ++nf)
          kv[nf] = kb[(size_t)(b0 + b_off + nf * 16 + l15) * ND + d];
      } else {
        #pragma unroll
        for (int nf = 0; nf < 4; ++nf) kv[nf] = 1.0f;
      }
    }

    #pragma unroll
    for (int c = 0; c < 4; ++c) {
      int chunk = w * 4 + c;
      int r = chunk * 8 + srow;
      gload_lds16(Wf8 + (size_t)(o0 + r) * KT2B + k0 + scol, &Als[chunk * 1024]);
      const unsigned char* gb = (d < ND)
          ? Xf8 + (size_t)(b0 + r) * IND_ + (k0 & 511) + scol
          : kbT8 + (size_t)(b0 + r) * 128 + scol;
      gload_lds16(gb, &Bls[chunk * 1024]);
    }
    __syncthreads();

    {
      i32x8 af[4], bfr[4];
      #pragma unroll
      for (int mf = 0; mf < 4; ++mf) {
        int rb = (o_off + mf * 16 + l15) * BKB;
        i32x4 lo = *reinterpret_cast<const i32x4*>(&Als[rb + s0]);
        i32x4 hi = *reinterpret_cast<const i32x4*>(&Als[rb + s1]);
        i32x8 v;
        v[0] = lo[0]; v[1] = lo[1]; v[2] = lo[2]; v[3] = lo[3];
        v[4] = hi[0]; v[5] = hi[1]; v[6] = hi[2]; v[7] = hi[3];
        af[mf] = v;
      }
      #pragma unroll
      for (int nf = 0; nf < 4; ++nf) {
        int rb = (b_off + nf * 16 + l15) * BKB;
        i32x4 lo = *reinterpret_cast<const i32x4*>(&Bls[rb + s0]);
        i32x4 hi = *reinterpret_cast<const i32x4*>(&Bls[rb + s1]);
        i32x8 v;
        v[0] = lo[0]; v[1] = lo[1]; v[2] = lo[2]; v[3] = lo[3];
        v[4] = hi[0]; v[5] = hi[1]; v[6] = hi[2]; v[7] = hi[3];
        bfr[nf] = v;
      }
      #pragma unroll
      for (int mf = 0; mf < 4; ++mf)
        #pragma unroll
        for (int nf = 0; nf < 4; ++nf)
          acc[mf][nf] = __builtin_amdgcn_mfma_scale_f32_16x16x128_f8f6f4(
              af[mf], bfr[nf], acc[mf][nf],
              0, 0, 0, 0x7f7f7f7f, 0, 0x7f7f7f7f);
    }
    __syncthreads();
  }

  #pragma unroll
  for (int nf = 0; nf < 4; ++nf)
    #pragma unroll
    for (int mf = 0; mf < 4; ++mf)
      #pragma unroll
      for (int r = 0; r < 4; ++r)
        fin[mf][nf][r] += kv[nf] * acc[mf][nf][r];

  unsigned short* Pz = Pb + (size_t)bz * NB * OUTD_;
  #pragma unroll
  for (int mf = 0; mf < 4; ++mf)
    #pragma unroll
    for (int nf = 0; nf < 4; ++nf) {
      int bg = b0 + b_off + nf * 16 + l15;
      int og = o0 + o_off + mf * 16 + quad * 4;
      u32x2 pk;
      pk[0] = pk_bf16(fin[mf][nf][0], fin[mf][nf][1]);
      pk[1] = pk_bf16(fin[mf][nf][2], fin[mf][nf][3]);
      *reinterpret_cast<u32x2*>(&Pz[(size_t)bg * OUTD_ + og]) = pk;
    }
}

// ---------------------------------------------------------------------------
// epilogue: out[b][2+o..2+o+3] = relu(P0+P1+P2+P3)  (bias in K-tail)
// ---------------------------------------------------------------------------
__global__ __launch_bounds__(256) void epilogue_kernel(
    const unsigned short* __restrict__ Pb, float* __restrict__ out)
{
  const int idx = (blockIdx.x * 256 + threadIdx.x) * 4;   // < 4096*512
  const int b = idx >> 9;
  const int o = idx & 511;
  const size_t ps = (size_t)NB * OUTD_;
  float s[4] = {0.0f, 0.0f, 0.0f, 0.0f};
  #pragma unroll
  for (int z = 0; z < NSPL; ++z) {
    u16x4 v = *reinterpret_cast<const u16x4*>(&Pb[z * ps + idx]);
    #pragma unroll
    for (int e = 0; e < 4; ++e) s[e] += bf2f(v[e]);
  }
  float* op = out + (size_t)b * XCOLS + 2 + o;   // 8B-aligned
  float2 lo, hi;
  lo.x = s[0] > 0.0f ? s[0] : 0.0f;
  lo.y = s[1] > 0.0f ? s[1] : 0.0f;
  hi.x = s[2] > 0.0f ? s[2] : 0.0f;
  hi.y = s[3] > 0.0f ? s[3] : 0.0f;
  *(float2*)op = lo;
  *(float2*)(op + 2) = hi;
}

// ---------------------------------------------------------------------------
extern "C" void kernel_launch(void* const* d_in, const int* in_sizes, int n_in,
                              void* d_out, int out_size, void* d_ws, size_t ws_size,
                              hipStream_t stream) {
  const float* x    = (const float*)d_in[0];   // 4096 x 514
  const float* W    = (const float*)d_in[1];   // 512 x 512 x 25
  const float* bias = (const float*)d_in[2];   // 512 x 25
  float* out = (float*)d_out;
  char* ws = (char*)d_ws;

  // ws layout (bytes):
  //   Xf8 2,097,152 | Wf8 512*12928 = 6,619,136 | kb 409,600
  //   kbT8 524,288 | Pb 4*4096*512*2 = 16,777,216   (total ~26.4 MB)
  const size_t xf_off  = 0;
  const size_t wf_off  = 2097152;
  const size_t kb_off  = wf_off + (size_t)OUTD_ * KT2B;
  const size_t kbt_off = kb_off + 409600;
  const size_t p_off   = kbt_off + (size_t)NB * 128;
  unsigned char* Xf8  = (unsigned char*)(ws + xf_off);
  unsigned char* Wf8  = (unsigned char*)(ws + wf_off);
  float* kb           = (float*)(ws + kb_off);
  unsigned char* kbT8 = (unsigned char*)(ws + kbt_off);
  unsigned short* Pb  = (unsigned short*)(ws + p_off);

  prep_all_kernel<<<1536, 256, 0, stream>>>(x, W, bias, Xf8, kb, kbT8, Wf8, out);
  gemm_mx_kernel<<<512, 256, 0, stream>>>(Wf8, Xf8, kb, kbT8, Pb);
  epilogue_kernel<<<(NB * OUTD_) / 1024, 256, 0, stream>>>(Pb, out);
}

// Round 19
// 124.181 us; speedup vs baseline: 1.6382x; 1.0247x over previous
//
#include <hip/hip_runtime.h>
#include <hip/hip_bf16.h>
#include <string.h>

// Problem constants
#define NB    4096      // batch rows
#define IND_  512       // feature dim
#define OUTD_ 512       // output dim (GEMM M, "o")
#define XCOLS 514       // P + IND
#define ND    25        // D^P
#define KTOT  12800     // IND_*ND
#define KT2B  12928     // KTOT + 128-col bias tail (fp8 bytes per Wf8 row)
#define NSPL  4         // split-K (R15-proven; R17's S=8 regressed)

// GEMM tiling
#define BM 128
#define BN 128
#define BKB 128         // K-window per iter (fp8 bytes == elements)

// prep_w tiling (R18-proven v2)
#define PWI 64
#define PWO 4
#define PWC (PWO * ND)   // 100 columns (o_l*25 + d)
#define T8P 112          // tile8 padded byte stride

typedef float  f32x4  __attribute__((ext_vector_type(4)));
typedef int    i32x4  __attribute__((ext_vector_type(4)));
typedef int    i32x8  __attribute__((ext_vector_type(8)));
typedef unsigned short u16x4 __attribute__((ext_vector_type(4)));
typedef unsigned int   u32x2 __attribute__((ext_vector_type(2)));

__device__ __forceinline__ unsigned short f2bf(float f) {
  unsigned int x = __float_as_uint(f);
  return (unsigned short)((x + 0x7fffu + ((x >> 16) & 1u)) >> 16);
}

__device__ __forceinline__ float bf2f(unsigned short u) {
  return __uint_as_float(((unsigned int)u) << 16);
}

__device__ __forceinline__ unsigned int pk_bf16(float a, float b) {
  return (unsigned int)f2bf(a) | ((unsigned int)f2bf(b) << 16);
}

// Software fp32 -> OCP e4m3fn, RNE, for v >= 0 (all values < 1.2).
__device__ __forceinline__ unsigned char f2fp8(float v) {
  if (v < 0.015625f) {
    return (unsigned char)__float2int_rn(v * 512.0f);
  }
  unsigned int u = __float_as_uint(v);
  u += 0x7ffffu + ((u >> 20) & 1u);
  int e = (int)(u >> 23) - 127 + 7;
  unsigned int m = (u >> 20) & 7u;
  return (unsigned char)((e << 3) | m);
}

__device__ __forceinline__ float basis_f(float t, int j) {
  switch (j) {
    case 0: return 1.0f;
    case 1: return t;
    case 2: return t * t;
    case 3: { float r = t - 0.33f; r = r > 0.0f ? r : 0.0f; return r * r; }
    default:{ float r = t - 0.66f; r = r > 0.0f ? r : 0.0f; return r * r; }
  }
}

__device__ __forceinline__ void gload_lds16(const void* g, void* l) {
  __builtin_amdgcn_global_load_lds(
      (const __attribute__((address_space(1))) void*)g,
      (__attribute__((address_space(3))) void*)l, 16, 0, 0);
}

// R7/R8 lesson: a pipelined K-loop (DMA issue hoisted above the MFMA block)
// MUST drain its own vmcnt explicitly before the barrier — the data is
// consumed by OTHER waves, and the compiler may otherwise tie the wait to
// this wave's first self-use after the barrier (R7: replay-dependent race).
__device__ __forceinline__ void drain_all() {
  asm volatile("s_waitcnt vmcnt(0) lgkmcnt(0)" ::: "memory");
}

// ---------------------------------------------------------------------------
// prep_all v2 (R18-proven, unchanged): 1536 blocks.
//   [0,512):    prep_x — 8 rows/block: Xf8, kb fp32, kbT8, out[0:2]
//   [512,1536): prep_w — balanced f2fp8 in load stage, byte-gather store;
//               i0==0 blocks also write bias K-tail.
// Lessons: R9/R16 — cross-block handoff = kernel boundary (grid.sync ~55us,
// fence storm ~3ms); R12 — no LDS unions.
// ---------------------------------------------------------------------------
__global__ __launch_bounds__(256) void prep_all_kernel(
    const float* __restrict__ x, const float* __restrict__ W,
    const float* __restrict__ bias, unsigned char* __restrict__ Xf8,
    float* __restrict__ kb, unsigned char* __restrict__ kbT8,
    unsigned char* __restrict__ Wf8, float* __restrict__ out)
{
  __shared__ unsigned char tile8[PWI * T8P];   // 7 KB
  const int bid = blockIdx.x;
  const int tid = threadIdx.x;

  if (bid < 512) {
    const int lane = tid & 63;
    #pragma unroll
    for (int rr = 0; rr < 2; ++rr) {
      const int b = bid * 8 + (tid >> 6) * 2 + rr;
      const float* xr = x + (size_t)b * XCOLS;
      const float* fp = xr + 2 + lane * 8;
      float2 a0 = *(const float2*)(fp + 0);
      float2 a1 = *(const float2*)(fp + 2);
      float2 a2 = *(const float2*)(fp + 4);
      float2 a3 = *(const float2*)(fp + 6);
      float xf[8] = {a0.x, a0.y, a1.x, a1.y, a2.x, a2.y, a3.x, a3.y};
      u32x2 pk;
      pk[0] = (unsigned int)f2fp8(xf[0]) | ((unsigned int)f2fp8(xf[1]) << 8) |
              ((unsigned int)f2fp8(xf[2]) << 16) | ((unsigned int)f2fp8(xf[3]) << 24);
      pk[1] = (unsigned int)f2fp8(xf[4]) | ((unsigned int)f2fp8(xf[5]) << 8) |
              ((unsigned int)f2fp8(xf[6]) << 16) | ((unsigned int)f2fp8(xf[7]) << 24);
      *reinterpret_cast<u32x2*>(Xf8 + (size_t)b * IND_ + lane * 8) = pk;

      float t0 = xr[0], t1 = xr[1];
      if (lane < 2) out[(size_t)b * XCOLS + lane] = (lane == 0) ? t0 : t1;
      {
        int d1 = lane / 5, d2 = lane - d1 * 5;
        float kv = basis_f(t0, d1) * basis_f(t1, d2);
        if (lane < ND) kb[(size_t)b * ND + lane] = kv;
      }
      {
        int ta = 2 * lane, tb = 2 * lane + 1;
        unsigned char ba = 0, bb = 0;
        if (ta < ND) { int d1 = ta / 5, d2 = ta - d1 * 5;
                       ba = f2fp8(basis_f(t0, d1) * basis_f(t1, d2)); }
        if (tb < ND) { int d1 = tb / 5, d2 = tb - d1 * 5;
                       bb = f2fp8(basis_f(t0, d1) * basis_f(t1, d2)); }
        *(unsigned short*)(kbT8 + (size_t)b * 128 + 2 * lane) =
            (unsigned short)ba | ((unsigned short)bb << 8);
      }
    }
  } else {
    const int pw = bid - 512;
    const int i0 = (pw & 7) * PWI;
    const int o0 = (pw >> 3) * PWO;

    for (int t = tid; t < PWI * (PWC / 4); t += 256) {
      int il = t / (PWC / 4);
      int c4 = t - il * (PWC / 4);
      float4 v = *(const float4*)(W + ((size_t)(i0 + il) * OUTD_ + o0) * ND + c4 * 4);
      unsigned int pk = (unsigned int)f2fp8(v.x) | ((unsigned int)f2fp8(v.y) << 8) |
                        ((unsigned int)f2fp8(v.z) << 16) | ((unsigned int)f2fp8(v.w) << 24);
      *(unsigned int*)&tile8[il * T8P + c4 * 4] = pk;
    }
    __syncthreads();

    for (int g = tid; g < PWC * (PWI / 8); g += 256) {
      int c  = g >> 3;
      int ig = g & 7;
      int d  = c % 25;
      int o_l = c / 25;
      unsigned long long v = 0;
      #pragma unroll
      for (int jj = 0; jj < 8; ++jj)
        v |= (unsigned long long)tile8[(ig * 8 + jj) * T8P + c] << (8 * jj);
      size_t rowb = (size_t)(o0 + o_l) * KT2B + (size_t)d * IND_ + i0;
      *reinterpret_cast<unsigned long long*>(Wf8 + rowb + ig * 8) = v;
    }

    if ((pw & 7) == 0) {
      int o = o0 + (tid >> 6);
      int p = tid & 63;
      int ta = 2 * p, tb = 2 * p + 1;
      unsigned char ba = (ta < ND) ? f2fp8(bias[o * ND + ta]) : (unsigned char)0;
      unsigned char bb = (tb < ND) ? f2fp8(bias[o * ND + tb]) : (unsigned char)0;
      *(unsigned short*)(Wf8 + (size_t)o * KT2B + KTOT + 2 * p) =
          (unsigned short)ba | ((unsigned short)bb << 8);
    }
  }
}

// ---------------------------------------------------------------------------
// gemm_mx v2: R15/R18 MX kernel with DOUBLE-BUFFERED 1-barrier K-loop.
// Old loop: [issue DMA; barrier(drain); MFMA; barrier] — full DMA latency
// exposed every iter (measured ~4200 cyc/iter vs ~1150 staging-BW bound).
// New loop: [issue DMA(n+1)->buf q; 16 MFMAs on buf p; drain_all; barrier]
// — DMA latency/BW overlapped by ~1100 cyc of MFMA; ONE barrier per iter.
// WAR safe: all waves' ds_reads of buf q finished before the PREVIOUS
// barrier.  Explicit drain before barrier per R7/R8 (cross-wave DMA
// visibility).  LDS 2x(16+16)=64KB -> still 2 blocks/CU with (256,2).
// ---------------------------------------------------------------------------
__global__ __launch_bounds__(256, 2) void gemm_mx_kernel(
    const unsigned char* __restrict__ Wf8, const unsigned char* __restrict__ Xf8,
    const float* __restrict__ kb, const unsigned char* __restrict__ kbT8,
    unsigned short* __restrict__ Pb)
{
  __shared__ unsigned char Als[2][BM * BKB];   // 2 x 16 KB
  __shared__ unsigned char Bls[2][BN * BKB];   // 2 x 16 KB

  const int tid  = threadIdx.x;
  const int lane = tid & 63;
  const int w    = tid >> 6;
  const int l15  = lane & 15;
  const int quad = lane >> 4;

  const int id  = blockIdx.x;           // [0,512)
  const int xcd = id & 7;
  const int j   = id >> 3;              // [0,64)
  const int bx  = j & 3;                // o-tile
  const int pg  = xcd * 16 + (j >> 2);  // [0,128): (b-tile, split)
  const int by  = pg & 31;
  const int bz  = pg >> 5;              // split [0,4)

  const int o0 = bx * BM;
  const int b0 = by * BN;
  const int ks_begin = bz * 3200;                   // 25 iters x 128
  const int ks_end   = (bz == 3) ? KT2B : ks_begin + 3200;
  const int nIter    = (ks_end - ks_begin) / BKB;   // 25 or 26

  const int o_off = (w & 1) * 64;
  const int b_off = (w >> 1) * 64;
  const int srow  = lane >> 3;
  const int scol  = ((lane & 7) ^ srow) * 16;
  const int r7    = l15 & 7;
  const int s0    = ((2 * quad) ^ r7) * 16;
  const int s1    = ((2 * quad + 1) ^ r7) * 16;

  f32x4 acc[4][4], fin[4][4];
  #pragma unroll
  for (int i = 0; i < 4; ++i)
    #pragma unroll
    for (int jj = 0; jj < 4; ++jj) { acc[i][jj] = (f32x4)0.0f; fin[i][jj] = (f32x4)0.0f; }

  float kv[4] = {1.0f, 1.0f, 1.0f, 1.0f};
  int cur_d = -1;

  // stage iters n (A) and n+? : issue both operands for K-window k0 into buf
  auto issueAB = [&](int k0, int buf) {
    const int dd = k0 >> 9;
    #pragma unroll
    for (int c = 0; c < 4; ++c) {
      int chunk = w * 4 + c;
      int r = chunk * 8 + srow;
      gload_lds16(Wf8 + (size_t)(o0 + r) * KT2B + k0 + scol, &Als[buf][chunk * 1024]);
      const unsigned char* gb = (dd < ND)
          ? Xf8 + (size_t)(b0 + r) * IND_ + (k0 & 511) + scol
          : kbT8 + (size_t)(b0 + r) * 128 + scol;
      gload_lds16(gb, &Bls[buf][chunk * 1024]);
    }
  };

  // prologue: fill buf 0
  issueAB(ks_begin, 0);
  drain_all();
  __syncthreads();

  for (int n = 0; n < nIter; ++n) {
    const int k0 = ks_begin + n * BKB;
    const int p  = n & 1;
    const int q  = p ^ 1;

    if (n + 1 < nIter) issueAB(k0 + BKB, q);   // overlaps MFMA below

    const int d = k0 >> 9;            // 25 => bias tail
    if (d != cur_d) {
      if (cur_d >= 0) {
        #pragma unroll
        for (int nf = 0; nf < 4; ++nf)
          #pragma unroll
          for (int mf = 0; mf < 4; ++mf)
            #pragma unroll
            for (int r = 0; r < 4; ++r) {
              fin[mf][nf][r] += kv[nf] * acc[mf][nf][r];
              acc[mf][nf][r] = 0.0f;
            }
      }
      cur_d = d;
      if (d < ND) {
        #pragma unroll
        for (int nf = 0; nf < 4; ++nf)
          kv[nf] = kb[(size_t)(b0 + b_off + nf * 16 + l15) * ND + d];
      } else {
        #pragma unroll
        for (int nf = 0; nf < 4; ++nf) kv[nf] = 1.0f;
      }
    }

    // 16 scaled MFMAs on buf p
    {
      i32x8 af[4], bfr[4];
      #pragma unroll
      for (int mf = 0; mf < 4; ++mf) {
        int rb = (o_off + mf * 16 + l15) * BKB;
        i32x4 lo = *reinterpret_cast<const i32x4*>(&Als[p][rb + s0]);
        i32x4 hi = *reinterpret_cast<const i32x4*>(&Als[p][rb + s1]);
        i32x8 v;
        v[0] = lo[0]; v[1] = lo[1]; v[2] = lo[2]; v[3] = lo[3];
        v[4] = hi[0]; v[5] = hi[1]; v[6] = hi[2]; v[7] = hi[3];
        af[mf] = v;
      }
      #pragma unroll
      for (int nf = 0; nf < 4; ++nf) {
        int rb = (b_off + nf * 16 + l15) * BKB;
        i32x4 lo = *reinterpret_cast<const i32x4*>(&Bls[p][rb + s0]);
        i32x4 hi = *reinterpret_cast<const i32x4*>(&Bls[p][rb + s1]);
        i32x8 v;
        v[0] = lo[0]; v[1] = lo[1]; v[2] = lo[2]; v[3] = lo[3];
        v[4] = hi[0]; v[5] = hi[1]; v[6] = hi[2]; v[7] = hi[3];
        bfr[nf] = v;
      }
      #pragma unroll
      for (int mf = 0; mf < 4; ++mf)
        #pragma unroll
        for (int nf = 0; nf < 4; ++nf)
          acc[mf][nf] = __builtin_amdgcn_mfma_scale_f32_16x16x128_f8f6f4(
              af[mf], bfr[nf], acc[mf][nf],
              0, 0, 0, 0x7f7f7f7f, 0, 0x7f7f7f7f);
    }

    drain_all();          // drain own DMA (issued above, overlapped by MFMA)
    __syncthreads();      // ONE barrier per iter
  }

  // final flush
  #pragma unroll
  for (int nf = 0; nf < 4; ++nf)
    #pragma unroll
    for (int mf = 0; mf < 4; ++mf)
      #pragma unroll
      for (int r = 0; r < 4; ++r)
        fin[mf][nf][r] += kv[nf] * acc[mf][nf][r];

  // store partial as bf16
  unsigned short* Pz = Pb + (size_t)bz * NB * OUTD_;
  #pragma unroll
  for (int mf = 0; mf < 4; ++mf)
    #pragma unroll
    for (int nf = 0; nf < 4; ++nf) {
      int bg = b0 + b_off + nf * 16 + l15;
      int og = o0 + o_off + mf * 16 + quad * 4;
      u32x2 pk;
      pk[0] = pk_bf16(fin[mf][nf][0], fin[mf][nf][1]);
      pk[1] = pk_bf16(fin[mf][nf][2], fin[mf][nf][3]);
      *reinterpret_cast<u32x2*>(&Pz[(size_t)bg * OUTD_ + og]) = pk;
    }
}

// ---------------------------------------------------------------------------
// epilogue: out[b][2+o..2+o+3] = relu(P0+P1+P2+P3)  (bias in K-tail)
// ---------------------------------------------------------------------------
__global__ __launch_bounds__(256) void epilogue_kernel(
    const unsigned short* __restrict__ Pb, float* __restrict__ out)
{
  const int idx = (blockIdx.x * 256 + threadIdx.x) * 4;   // < 4096*512
  const int b = idx >> 9;
  const int o = idx & 511;
  const size_t ps = (size_t)NB * OUTD_;
  float s[4] = {0.0f, 0.0f, 0.0f, 0.0f};
  #pragma unroll
  for (int z = 0; z < NSPL; ++z) {
    u16x4 v = *reinterpret_cast<const u16x4*>(&Pb[z * ps + idx]);
    #pragma unroll
    for (int e = 0; e < 4; ++e) s[e] += bf2f(v[e]);
  }
  float* op = out + (size_t)b * XCOLS + 2 + o;   // 8B-aligned
  float2 lo, hi;
  lo.x = s[0] > 0.0f ? s[0] : 0.0f;
  lo.y = s[1] > 0.0f ? s[1] : 0.0f;
  hi.x = s[2] > 0.0f ? s[2] : 0.0f;
  hi.y = s[3] > 0.0f ? s[3] : 0.0f;
  *(float2*)op = lo;
  *(float2*)(op + 2) = hi;
}

// ---------------------------------------------------------------------------
extern "C" void kernel_launch(void* const* d_in, const int* in_sizes, int n_in,
                              void* d_out, int out_size, void* d_ws, size_t ws_size,
                              hipStream_t stream) {
  const float* x    = (const float*)d_in[0];   // 4096 x 514
  const float* W    = (const float*)d_in[1];   // 512 x 512 x 25
  const float* bias = (const float*)d_in[2];   // 512 x 25
  float* out = (float*)d_out;
  char* ws = (char*)d_ws;

  // ws layout (bytes):
  //   Xf8 2,097,152 | Wf8 512*12928 = 6,619,136 | kb 409,600
  //   kbT8 524,288 | Pb 4*4096*512*2 = 16,777,216   (total ~26.4 MB)
  const size_t xf_off  = 0;
  const size_t wf_off  = 2097152;
  const size_t kb_off  = wf_off + (size_t)OUTD_ * KT2B;
  const size_t kbt_off = kb_off + 409600;
  const size_t p_off   = kbt_off + (size_t)NB * 128;
  unsigned char* Xf8  = (unsigned char*)(ws + xf_off);
  unsigned char* Wf8  = (unsigned char*)(ws + wf_off);
  float* kb           = (float*)(ws + kb_off);
  unsigned char* kbT8 = (unsigned char*)(ws + kbt_off);
  unsigned short* Pb  = (unsigned short*)(ws + p_off);

  prep_all_kernel<<<1536, 256, 0, stream>>>(x, W, bias, Xf8, kb, kbT8, Wf8, out);
  gemm_mx_kernel<<<512, 256, 0, stream>>>(Wf8, Xf8, kb, kbT8, Pb);
  epilogue_kernel<<<(NB * OUTD_) / 1024, 256, 0, stream>>>(Pb, out);
}